// Round 21
// baseline (209.398 us; speedup 1.0000x reference)
//
#include <hip/hip_runtime.h>
#include <hip/hip_bf16.h>

typedef __bf16 bf16_t;
typedef __bf16 bf16x8 __attribute__((ext_vector_type(8)));
typedef __bf16 bf16x4 __attribute__((ext_vector_type(4)));
typedef float  f32x4  __attribute__((ext_vector_type(4)));

#define D 128
#define UV_LDS 131072   // uv_kernel: 64KB weights + 8 x 8KB chunks

// LDS element-index swizzle: XOR multiples of 8 elems (16B) keep 4/8-elem groups intact.
__device__ __forceinline__ int swz(int r, int c) {
    return (r * D + c) ^ ((r & 7) << 3);
}

// prep: blocks 0..255: 4 transposed slice-major weight tiles ws[s][c][k]
//       blocks 256..271: fragment-packed W1c/W2 for the edge kernel:
//       wsf[((g*4+kk)*8+n)*64 + lane] (bf16x8) = Wt_g[n*16+(lane&15)][kk*32+(lane>>4)*8 ..+8]
__global__ void prep_weights_kernel(const float* __restrict__ W1,
                                    const float* __restrict__ W2,
                                    bf16_t* __restrict__ ws,
                                    bf16_t* __restrict__ wsf) {
    int b = blockIdx.x;
    if (b < 256) {
        int t = b * 256 + threadIdx.x;
        int s = t >> 14, r = t & 16383;
        int n = r >> 7, k = r & 127;
        float v = (s < 3) ? W1[(s * 128 + k) * 128 + n] : W2[k * 128 + n];
        ws[t] = (bf16_t)v;
    } else {
        int t = (b - 256) * 256 + threadIdx.x;      // 0..4095
        int lane = t & 63, f = t >> 6;              // f = (g*4+kk)*8+n
        int n = f & 7, kk = (f >> 3) & 3, g = f >> 5;
        int c = n * 16 + (lane & 15);
        int k0 = kk * 32 + (lane >> 4) * 8;
        bf16x8 v;
#pragma unroll
        for (int j = 0; j < 8; j++) {
            int k = k0 + j;
            float w = (g == 0) ? W1[(256 + k) * 128 + c] : W2[k * 128 + c];
            v[j] = (bf16_t)w;
        }
        *(bf16x8*)(wsf + t * 8) = v;
    }
}

// u = x·W1a + b1, v = x·W1b   (bf16 row-major, gather-ready)  [proven R10 kernel]
__global__ __launch_bounds__(512, 2)
void uv_kernel(const float* __restrict__ x, const bf16_t* __restrict__ ws,
               const float* __restrict__ b1, bf16_t* __restrict__ u,
               bf16_t* __restrict__ v, int N) {
    extern __shared__ __align__(16) bf16_t lds[];
    const int tid = threadIdx.x, lane = tid & 63, wv = tid >> 6;
    const int col0 = lane & 15, krow = lane >> 4, l31 = lane & 31, half = lane >> 5;
    const int gr = lane >> 4, gc = (lane & 15) * 8;
    const int n0 = blockIdx.x * 256 + wv * 32;
    bf16_t* Ach = lds + 32768 + wv * 4096;

    f32x4 xb[16];
#pragma unroll
    for (int j = 0; j < 16; j++) {
        int node = min(n0 + j * 2 + half, N - 1);
        xb[j] = *(const f32x4*)(x + (long long)node * D + l31 * 4);
    }
#pragma unroll
    for (int s = 0; s < 2; s++)
#pragma unroll
        for (int j = 0; j < 4; j++) {
            int row = j * 32 + (tid >> 4), slot = (tid & 15) * 8;
            bf16x8 w = *(const bf16x8*)(ws + s * 16384 + row * 128 + slot);
            *(bf16x8*)&lds[s * 16384 + swz(row, slot)] = w;
        }
    float bias1[8];
#pragma unroll
    for (int n = 0; n < 8; n++) bias1[n] = b1[n * 16 + col0];
#pragma unroll
    for (int j = 0; j < 16; j++) {
        f32x4 vv = xb[j];
        bf16x4 hv = { (bf16_t)vv.x, (bf16_t)vv.y, (bf16_t)vv.z, (bf16_t)vv.w };
        *(bf16x4*)&Ach[swz(j * 2 + half, l31 * 4)] = hv;
    }
    __syncthreads();

    f32x4 aU[2][8], aV[2][8];
#pragma unroll
    for (int m = 0; m < 2; m++)
#pragma unroll
        for (int n = 0; n < 8; n++) { aU[m][n] = (f32x4){0,0,0,0}; aV[m][n] = (f32x4){0,0,0,0}; }
#pragma unroll
    for (int kk = 0; kk < 4; kk++) {
        bf16x8 a0 = *(const bf16x8*)&Ach[swz(col0, kk*32 + krow*8)];
        bf16x8 a1 = *(const bf16x8*)&Ach[swz(16 + col0, kk*32 + krow*8)];
#pragma unroll
        for (int n = 0; n < 8; n++) {
            bf16x8 bU = *(const bf16x8*)&lds[swz(n*16 + col0, kk*32 + krow*8)];
            bf16x8 bV = *(const bf16x8*)&lds[16384 + swz(n*16 + col0, kk*32 + krow*8)];
            aU[0][n] = __builtin_amdgcn_mfma_f32_16x16x32_bf16(a0, bU, aU[0][n], 0,0,0);
            aU[1][n] = __builtin_amdgcn_mfma_f32_16x16x32_bf16(a1, bU, aU[1][n], 0,0,0);
            aV[0][n] = __builtin_amdgcn_mfma_f32_16x16x32_bf16(a0, bV, aV[0][n], 0,0,0);
            aV[1][n] = __builtin_amdgcn_mfma_f32_16x16x32_bf16(a1, bV, aV[1][n], 0,0,0);
        }
    }
#pragma unroll
    for (int m = 0; m < 2; m++)
#pragma unroll
        for (int n = 0; n < 8; n++)
#pragma unroll
            for (int ri = 0; ri < 4; ri++)
                Ach[swz(m*16 + krow*4 + ri, n*16 + col0)] = (bf16_t)(aU[m][n][ri] + bias1[n]);
#pragma unroll
    for (int j = 0; j < 8; j++) {
        int r = j * 4 + gr, node = n0 + r;
        if (node < N) *(bf16x8*)(u + (long long)node * D + gc) = *(const bf16x8*)&Ach[swz(r, gc)];
    }
#pragma unroll
    for (int m = 0; m < 2; m++)
#pragma unroll
        for (int n = 0; n < 8; n++)
#pragma unroll
            for (int ri = 0; ri < 4; ri++)
                Ach[swz(m*16 + krow*4 + ri, n*16 + col0)] = (bf16_t)(aV[m][n][ri]);
#pragma unroll
    for (int j = 0; j < 8; j++) {
        int r = j * 4 + gr, node = n0 + r;
        if (node < N) *(bf16x8*)(v + (long long)node * D + gc) = *(const bf16x8*)&Ach[swz(r, gc)];
    }
}

// PERSISTENT edge kernel: 768 blocks grid-stride over 64-edge super-tiles.
// Each iteration = R20 body (2 independent 32-edge tiles, 4 waves, B in regs/L1).
// Loop-carried software pipeline: ea(st+stride) + ei(st+stride) issue into the
// registers freed by ea(st)->LDS, so steady-state iterations never wait on ea.
// out = relu( relu(ea·W1c + u[src] + v[dst]) · W2 + b2 )
__global__ __launch_bounds__(256, 3)
void edge_kernel(const bf16_t* __restrict__ u, const bf16_t* __restrict__ v,
                 const float* __restrict__ ea, const int* __restrict__ ei,
                 const bf16_t* __restrict__ wsf, const float* __restrict__ b2,
                 float* __restrict__ out, int E) {
    __shared__ __align__(16) bf16_t Ach[2][32 * D];   // ea tiles (bf16, swizzled)
    __shared__ __align__(16) bf16_t Hch[2][32 * D];   // p then h tiles

    const int tid  = threadIdx.x, lane = tid & 63, wv = tid >> 6;   // 4 waves
    const int col0 = lane & 15, krow = lane >> 4, l31 = lane & 31;

    const int nst    = (E + 63) >> 6;     // 6250 super-tiles of 64 edges
    const int stride = gridDim.x;         // 768
    int st = blockIdx.x;
    if (st >= nst) return;

    float bias2[2];
    bias2[0] = b2[wv * 32 + col0];
    bias2[1] = b2[wv * 32 + 16 + col0];

    // ---- prologue: ea(st) + ei(st) ----
    f32x4 eaR[2][4];
    int sidx[2], didx[2];
    {
        const int e0 = st * 64;
#pragma unroll
        for (int c = 0; c < 2; c++) {
#pragma unroll
            for (int j = 0; j < 4; j++) {
                int r = wv * 8 + j * 2 + (lane >> 5);
                int e = min(e0 + c * 32 + r, E - 1);
                eaR[c][j] = *(const f32x4*)(ea + (long long)e * D + l31 * 4);
            }
            int er8 = min(e0 + c * 32 + wv * 8 + (lane & 7), E - 1);
            sidx[c] = ei[er8];
            didx[c] = ei[E + er8];
        }
    }

    for (; st < nst; st += stride) {
        const int stn = st + stride;
        const int e0  = st * 64;

        // ---- ea(st) -> Ach; then issue ea(st+stride)+ei(st+stride) into freed regs ----
#pragma unroll
        for (int c = 0; c < 2; c++)
#pragma unroll
            for (int j = 0; j < 4; j++) {
                int r = wv * 8 + j * 2 + (lane >> 5);
                f32x4 vv = eaR[c][j];
                bf16x4 hv = { (bf16_t)vv.x, (bf16_t)vv.y, (bf16_t)vv.z, (bf16_t)vv.w };
                *(bf16x4*)&Ach[c][swz(r, l31 * 4)] = hv;
            }
        int sidxN[2], didxN[2];
        if (stn < nst) {
            const int e0n = stn * 64;
#pragma unroll
            for (int c = 0; c < 2; c++) {
#pragma unroll
                for (int j = 0; j < 4; j++) {
                    int r = wv * 8 + j * 2 + (lane >> 5);
                    int e = min(e0n + c * 32 + r, E - 1);
                    eaR[c][j] = *(const f32x4*)(ea + (long long)e * D + l31 * 4);
                }
                int er8 = min(e0n + c * 32 + wv * 8 + (lane & 7), E - 1);
                sidxN[c] = ei[er8];
                didxN[c] = ei[E + er8];
            }
        } else {
            sidxN[0] = sidxN[1] = didxN[0] = didxN[1] = 0;
        }
        __syncthreads();   // barrier 1: Ach ready (prev iter's Hch readers also done)

        // ---- u/v gathers (current tile) + B1 after the drain: fly under A1 ----
        bf16x8 uR[2][2], vR[2][2];
#pragma unroll
        for (int c = 0; c < 2; c++)
#pragma unroll
            for (int j = 0; j < 2; j++) {
                int gi = __shfl(sidx[c], j * 4 + (lane >> 4));   // 4 rows/instr, 256B/row
                uR[c][j] = *(const bf16x8*)(u + (long long)gi * D + col0 * 8);
                int gj = __shfl(didx[c], j * 4 + (lane >> 4));
                vR[c][j] = *(const bf16x8*)(v + (long long)gj * D + col0 * 8);
            }
        bf16x8 B1[4][2];
#pragma unroll
        for (int kk = 0; kk < 4; kk++)
#pragma unroll
            for (int j = 0; j < 2; j++)
                B1[kk][j] = *(const bf16x8*)(wsf + (((kk) * 8 + (wv * 2 + j)) * 64 + lane) * 8);

        // ---- A1 both tiles: p = ea · W1c ----
        f32x4 acc[2][2][2];   // [tile][m][j]
#pragma unroll
        for (int c = 0; c < 2; c++)
#pragma unroll
            for (int m = 0; m < 2; m++)
#pragma unroll
                for (int j = 0; j < 2; j++) acc[c][m][j] = (f32x4){0,0,0,0};
#pragma unroll
        for (int kk = 0; kk < 4; kk++) {
#pragma unroll
            for (int c = 0; c < 2; c++) {
                bf16x8 a0 = *(const bf16x8*)&Ach[c][swz(     col0, kk*32 + krow*8)];
                bf16x8 a1 = *(const bf16x8*)&Ach[c][swz(16 + col0, kk*32 + krow*8)];
#pragma unroll
                for (int j = 0; j < 2; j++) {
                    acc[c][0][j] = __builtin_amdgcn_mfma_f32_16x16x32_bf16(a0, B1[kk][j], acc[c][0][j], 0,0,0);
                    acc[c][1][j] = __builtin_amdgcn_mfma_f32_16x16x32_bf16(a1, B1[kk][j], acc[c][1][j], 0,0,0);
                }
            }
        }
        // p -> Hch (C-space scalar writes), both tiles
#pragma unroll
        for (int c = 0; c < 2; c++)
#pragma unroll
            for (int m = 0; m < 2; m++)
#pragma unroll
                for (int j = 0; j < 2; j++)
#pragma unroll
                    for (int ri = 0; ri < 4; ri++)
                        Hch[c][swz(m*16 + krow*4 + ri, wv*32 + j*16 + col0)] = (bf16_t)acc[c][m][j][ri];
        __syncthreads();   // barrier 2

        // ---- h = relu(p + u + v), both tiles (row-space b128 RMW, fused in regs) ----
#pragma unroll
        for (int c = 0; c < 2; c++)
#pragma unroll
            for (int j = 0; j < 2; j++) {
                int r = wv * 8 + j * 4 + (lane >> 4);
                bf16x8 p8 = *(const bf16x8*)&Hch[c][swz(r, col0 * 8)];
                bf16x8 h8;
#pragma unroll
                for (int t = 0; t < 8; t++)
                    h8[t] = (bf16_t)fmaxf((float)p8[t] + (float)uR[c][j][t] + (float)vR[c][j][t], 0.f);
                *(bf16x8*)&Hch[c][swz(r, col0 * 8)] = h8;
            }
        __syncthreads();   // barrier 3

        // ---- A2 both tiles: out = h · W2 ----
        bf16x8 B2[4][2];
#pragma unroll
        for (int kk = 0; kk < 4; kk++)
#pragma unroll
            for (int j = 0; j < 2; j++)
                B2[kk][j] = *(const bf16x8*)(wsf + (((4 + kk) * 8 + (wv * 2 + j)) * 64 + lane) * 8);
#pragma unroll
        for (int c = 0; c < 2; c++)
#pragma unroll
            for (int m = 0; m < 2; m++)
#pragma unroll
                for (int j = 0; j < 2; j++) acc[c][m][j] = (f32x4){0,0,0,0};
#pragma unroll
        for (int kk = 0; kk < 4; kk++) {
#pragma unroll
            for (int c = 0; c < 2; c++) {
                bf16x8 a0 = *(const bf16x8*)&Hch[c][swz(     col0, kk*32 + krow*8)];
                bf16x8 a1 = *(const bf16x8*)&Hch[c][swz(16 + col0, kk*32 + krow*8)];
#pragma unroll
                for (int j = 0; j < 2; j++) {
                    acc[c][0][j] = __builtin_amdgcn_mfma_f32_16x16x32_bf16(a0, B2[kk][j], acc[c][0][j], 0,0,0);
                    acc[c][1][j] = __builtin_amdgcn_mfma_f32_16x16x32_bf16(a1, B2[kk][j], acc[c][1][j], 0,0,0);
                }
            }
        }
        // epilogue both tiles: out = relu(acc + b2)
#pragma unroll
        for (int c = 0; c < 2; c++)
#pragma unroll
            for (int m = 0; m < 2; m++)
#pragma unroll
                for (int j = 0; j < 2; j++)
#pragma unroll
                    for (int ri = 0; ri < 4; ri++) {
                        int e = e0 + c * 32 + m*16 + krow*4 + ri;
                        if (e < E)
                            out[(long long)e * D + wv*32 + j*16 + col0] = fmaxf(acc[c][m][j][ri] + bias2[j], 0.f);
                    }

        // rotate pipeline state
        sidx[0] = sidxN[0]; sidx[1] = sidxN[1];
        didx[0] = didxN[0]; didx[1] = didxN[1];
        // no barrier needed: next iter's Ach writes are safe (A1 reads done before
        // barrier 2), and next p->Hch writes happen only after next barrier 1,
        // by which time all waves' A2 reads of Hch have completed.
    }
}

extern "C" void kernel_launch(void* const* d_in, const int* in_sizes, int n_in,
                              void* d_out, int out_size, void* d_ws, size_t ws_size,
                              hipStream_t stream) {
    const float* x  = (const float*)d_in[0];
    const float* ea = (const float*)d_in[1];
    const int*   ei = (const int*)d_in[2];
    const float* W1 = (const float*)d_in[3];
    const float* b1 = (const float*)d_in[4];
    const float* W2 = (const float*)d_in[5];
    const float* b2 = (const float*)d_in[6];
    float* out = (float*)d_out;

    const int E = in_sizes[1] / D;      // 400000
    const int N = in_sizes[0] / D;      // 50000

    bf16_t* wsl = (bf16_t*)d_ws;                  // 128 KB: slice-major tiles (uv_kernel)
    bf16_t* wsf = wsl + 4 * 16384;                // 64 KB: fragment-packed W1c/W2 (edge)
    bf16_t* uu  = wsf + 32768;                    // N*128 bf16
    bf16_t* vv  = uu + (size_t)N * D;             // N*128 bf16

    prep_weights_kernel<<<272, 256, 0, stream>>>(W1, W2, wsl, wsf);

    hipFuncSetAttribute(reinterpret_cast<const void*>(uv_kernel),
                        hipFuncAttributeMaxDynamicSharedMemorySize, UV_LDS);
    uv_kernel<<<(N + 255) / 256, 512, UV_LDS, stream>>>(x, wsl, b1, uu, vv, N);

    edge_kernel<<<768, 256, 0, stream>>>(uu, vv, ea, ei, wsf, b2, out, E);
}

// Round 22
// 131.050 us; speedup vs baseline: 1.5978x; 1.5978x over previous
//
#include <hip/hip_runtime.h>
#include <hip/hip_bf16.h>

typedef __bf16 bf16_t;
typedef __bf16 bf16x8 __attribute__((ext_vector_type(8)));
typedef __bf16 bf16x4 __attribute__((ext_vector_type(4)));
typedef float  f32x4  __attribute__((ext_vector_type(4)));

#define D 128
#define UV_LDS 131072   // uv_kernel: 64KB weights + 8 x 8KB chunks

// LDS element-index swizzle: XOR multiples of 8 elems (16B) keep 4/8-elem groups intact.
__device__ __forceinline__ int swz(int r, int c) {
    return (r * D + c) ^ ((r & 7) << 3);
}

// prep: blocks 0..255: 4 transposed slice-major weight tiles ws[s][c][k]
//       blocks 256..271: fragment-packed W1c/W2 for the edge kernel:
//       wsf[((g*4+kk)*8+n)*64 + lane] (bf16x8) = Wt_g[n*16+(lane&15)][kk*32+(lane>>4)*8 ..+8]
__global__ void prep_weights_kernel(const float* __restrict__ W1,
                                    const float* __restrict__ W2,
                                    bf16_t* __restrict__ ws,
                                    bf16_t* __restrict__ wsf) {
    int b = blockIdx.x;
    if (b < 256) {
        int t = b * 256 + threadIdx.x;
        int s = t >> 14, r = t & 16383;
        int n = r >> 7, k = r & 127;
        float v = (s < 3) ? W1[(s * 128 + k) * 128 + n] : W2[k * 128 + n];
        ws[t] = (bf16_t)v;
    } else {
        int t = (b - 256) * 256 + threadIdx.x;      // 0..4095
        int lane = t & 63, f = t >> 6;              // f = (g*4+kk)*8+n
        int n = f & 7, kk = (f >> 3) & 3, g = f >> 5;
        int c = n * 16 + (lane & 15);
        int k0 = kk * 32 + (lane >> 4) * 8;
        bf16x8 v;
#pragma unroll
        for (int j = 0; j < 8; j++) {
            int k = k0 + j;
            float w = (g == 0) ? W1[(256 + k) * 128 + c] : W2[k * 128 + c];
            v[j] = (bf16_t)w;
        }
        *(bf16x8*)(wsf + t * 8) = v;
    }
}

// u = x·W1a + b1, v = x·W1b   (bf16 row-major, gather-ready)  [proven R10 kernel]
// x loads are non-temporal (single-use stream) to keep L2/L3 clean.
__global__ __launch_bounds__(512, 2)
void uv_kernel(const float* __restrict__ x, const bf16_t* __restrict__ ws,
               const float* __restrict__ b1, bf16_t* __restrict__ u,
               bf16_t* __restrict__ v, int N) {
    extern __shared__ __align__(16) bf16_t lds[];
    const int tid = threadIdx.x, lane = tid & 63, wv = tid >> 6;
    const int col0 = lane & 15, krow = lane >> 4, l31 = lane & 31, half = lane >> 5;
    const int gr = lane >> 4, gc = (lane & 15) * 8;
    const int n0 = blockIdx.x * 256 + wv * 32;
    bf16_t* Ach = lds + 32768 + wv * 4096;

    f32x4 xb[16];
#pragma unroll
    for (int j = 0; j < 16; j++) {
        int node = min(n0 + j * 2 + half, N - 1);
        xb[j] = __builtin_nontemporal_load((const f32x4*)(x + (long long)node * D + l31 * 4));
    }
#pragma unroll
    for (int s = 0; s < 2; s++)
#pragma unroll
        for (int j = 0; j < 4; j++) {
            int row = j * 32 + (tid >> 4), slot = (tid & 15) * 8;
            bf16x8 w = *(const bf16x8*)(ws + s * 16384 + row * 128 + slot);
            *(bf16x8*)&lds[s * 16384 + swz(row, slot)] = w;
        }
    float bias1[8];
#pragma unroll
    for (int n = 0; n < 8; n++) bias1[n] = b1[n * 16 + col0];
#pragma unroll
    for (int j = 0; j < 16; j++) {
        f32x4 vv = xb[j];
        bf16x4 hv = { (bf16_t)vv.x, (bf16_t)vv.y, (bf16_t)vv.z, (bf16_t)vv.w };
        *(bf16x4*)&Ach[swz(j * 2 + half, l31 * 4)] = hv;
    }
    __syncthreads();

    f32x4 aU[2][8], aV[2][8];
#pragma unroll
    for (int m = 0; m < 2; m++)
#pragma unroll
        for (int n = 0; n < 8; n++) { aU[m][n] = (f32x4){0,0,0,0}; aV[m][n] = (f32x4){0,0,0,0}; }
#pragma unroll
    for (int kk = 0; kk < 4; kk++) {
        bf16x8 a0 = *(const bf16x8*)&Ach[swz(col0, kk*32 + krow*8)];
        bf16x8 a1 = *(const bf16x8*)&Ach[swz(16 + col0, kk*32 + krow*8)];
#pragma unroll
        for (int n = 0; n < 8; n++) {
            bf16x8 bU = *(const bf16x8*)&lds[swz(n*16 + col0, kk*32 + krow*8)];
            bf16x8 bV = *(const bf16x8*)&lds[16384 + swz(n*16 + col0, kk*32 + krow*8)];
            aU[0][n] = __builtin_amdgcn_mfma_f32_16x16x32_bf16(a0, bU, aU[0][n], 0,0,0);
            aU[1][n] = __builtin_amdgcn_mfma_f32_16x16x32_bf16(a1, bU, aU[1][n], 0,0,0);
            aV[0][n] = __builtin_amdgcn_mfma_f32_16x16x32_bf16(a0, bV, aV[0][n], 0,0,0);
            aV[1][n] = __builtin_amdgcn_mfma_f32_16x16x32_bf16(a1, bV, aV[1][n], 0,0,0);
        }
    }
#pragma unroll
    for (int m = 0; m < 2; m++)
#pragma unroll
        for (int n = 0; n < 8; n++)
#pragma unroll
            for (int ri = 0; ri < 4; ri++)
                Ach[swz(m*16 + krow*4 + ri, n*16 + col0)] = (bf16_t)(aU[m][n][ri] + bias1[n]);
#pragma unroll
    for (int j = 0; j < 8; j++) {
        int r = j * 4 + gr, node = n0 + r;
        if (node < N) *(bf16x8*)(u + (long long)node * D + gc) = *(const bf16x8*)&Ach[swz(r, gc)];
    }
#pragma unroll
    for (int m = 0; m < 2; m++)
#pragma unroll
        for (int n = 0; n < 8; n++)
#pragma unroll
            for (int ri = 0; ri < 4; ri++)
                Ach[swz(m*16 + krow*4 + ri, n*16 + col0)] = (bf16_t)(aV[m][n][ri]);
#pragma unroll
    for (int j = 0; j < 8; j++) {
        int r = j * 4 + gr, node = n0 + r;
        if (node < N) *(bf16x8*)(v + (long long)node * D + gc) = *(const bf16x8*)&Ach[swz(r, gc)];
    }
}

// Two independent 32-edge tiles per block, 4 waves; wave wv owns output cols
// [wv*32, wv*32+32) of both tiles. B-fragments in regs/L1.
// NON-TEMPORAL streams: ea loads + out stores bypass cache allocation, so
// L2/L3 stay reserved for the u/v gather hot set (51 MB << 256 MB L3).
// out = relu( relu(ea·W1c + u[src] + v[dst]) · W2 + b2 )
__global__ __launch_bounds__(256, 3)
void edge_kernel(const bf16_t* __restrict__ u, const bf16_t* __restrict__ v,
                 const float* __restrict__ ea, const int* __restrict__ ei,
                 const bf16_t* __restrict__ wsf, const float* __restrict__ b2,
                 float* __restrict__ out, int E) {
    __shared__ __align__(16) bf16_t Ach[2][32 * D];   // ea tiles (bf16, swizzled)
    __shared__ __align__(16) bf16_t Hch[2][32 * D];   // p then h tiles

    const int tid  = threadIdx.x, lane = tid & 63, wv = tid >> 6;   // 4 waves
    const int col0 = lane & 15, krow = lane >> 4, l31 = lane & 31;
    const int e0   = blockIdx.x * 64;                // tile c: rows e0 + c*32 ..

    // ---- prologue: ea loads (non-temporal) + indices + B1 only ----
    f32x4 eaR[2][4];
#pragma unroll
    for (int c = 0; c < 2; c++)
#pragma unroll
        for (int j = 0; j < 4; j++) {
            int r = wv * 8 + j * 2 + (lane >> 5);
            int e = min(e0 + c * 32 + r, E - 1);
            eaR[c][j] = __builtin_nontemporal_load((const f32x4*)(ea + (long long)e * D + l31 * 4));
        }
    int sidx[2], didx[2];
#pragma unroll
    for (int c = 0; c < 2; c++) {
        int er8 = min(e0 + c * 32 + wv * 8 + (lane & 7), E - 1);
        sidx[c] = ei[er8];
        didx[c] = ei[E + er8];
    }
    bf16x8 B1[4][2];
#pragma unroll
    for (int kk = 0; kk < 4; kk++)
#pragma unroll
        for (int j = 0; j < 2; j++)
            B1[kk][j] = *(const bf16x8*)(wsf + (((kk) * 8 + (wv * 2 + j)) * 64 + lane) * 8);
    float bias2[2];
    bias2[0] = b2[wv * 32 + col0];
    bias2[1] = b2[wv * 32 + 16 + col0];

    // ---- ea -> Ach (both tiles) ----
#pragma unroll
    for (int c = 0; c < 2; c++)
#pragma unroll
        for (int j = 0; j < 4; j++) {
            int r = wv * 8 + j * 2 + (lane >> 5);
            f32x4 vv = eaR[c][j];
            bf16x4 hv = { (bf16_t)vv.x, (bf16_t)vv.y, (bf16_t)vv.z, (bf16_t)vv.w };
            *(bf16x4*)&Ach[c][swz(r, l31 * 4)] = hv;
        }
    __syncthreads();   // barrier 1 (drains ea/ei/B1 — all needed right now anyway)

    // ---- issue u/v gathers + B2 AFTER the drain: they fly under A1 + p-writes ----
    bf16x8 uR[2][2], vR[2][2];
#pragma unroll
    for (int c = 0; c < 2; c++)
#pragma unroll
        for (int j = 0; j < 2; j++) {
            int gi = __shfl(sidx[c], j * 4 + (lane >> 4));   // 4 rows/instr, 256B/row
            uR[c][j] = *(const bf16x8*)(u + (long long)gi * D + col0 * 8);
            int gj = __shfl(didx[c], j * 4 + (lane >> 4));
            vR[c][j] = *(const bf16x8*)(v + (long long)gj * D + col0 * 8);
        }
    bf16x8 B2[4][2];
#pragma unroll
    for (int kk = 0; kk < 4; kk++)
#pragma unroll
        for (int j = 0; j < 2; j++)
            B2[kk][j] = *(const bf16x8*)(wsf + (((4 + kk) * 8 + (wv * 2 + j)) * 64 + lane) * 8);

    // ---- A1 both tiles: p = ea · W1c ----
    f32x4 acc[2][2][2];   // [tile][m][j]
#pragma unroll
    for (int c = 0; c < 2; c++)
#pragma unroll
        for (int m = 0; m < 2; m++)
#pragma unroll
            for (int j = 0; j < 2; j++) acc[c][m][j] = (f32x4){0,0,0,0};
#pragma unroll
    for (int kk = 0; kk < 4; kk++) {
#pragma unroll
        for (int c = 0; c < 2; c++) {
            bf16x8 a0 = *(const bf16x8*)&Ach[c][swz(     col0, kk*32 + krow*8)];
            bf16x8 a1 = *(const bf16x8*)&Ach[c][swz(16 + col0, kk*32 + krow*8)];
#pragma unroll
            for (int j = 0; j < 2; j++) {
                acc[c][0][j] = __builtin_amdgcn_mfma_f32_16x16x32_bf16(a0, B1[kk][j], acc[c][0][j], 0,0,0);
                acc[c][1][j] = __builtin_amdgcn_mfma_f32_16x16x32_bf16(a1, B1[kk][j], acc[c][1][j], 0,0,0);
            }
        }
    }
    // p -> Hch (C-space scalar writes), both tiles
#pragma unroll
    for (int c = 0; c < 2; c++)
#pragma unroll
        for (int m = 0; m < 2; m++)
#pragma unroll
            for (int j = 0; j < 2; j++)
#pragma unroll
                for (int ri = 0; ri < 4; ri++)
                    Hch[c][swz(m*16 + krow*4 + ri, wv*32 + j*16 + col0)] = (bf16_t)acc[c][m][j][ri];
    __syncthreads();   // barrier 2

    // ---- h = relu(p + u + v), both tiles (row-space b128 RMW, fused in regs) ----
#pragma unroll
    for (int c = 0; c < 2; c++)
#pragma unroll
        for (int j = 0; j < 2; j++) {
            int r = wv * 8 + j * 4 + (lane >> 4);
            bf16x8 p8 = *(const bf16x8*)&Hch[c][swz(r, col0 * 8)];
            bf16x8 h8;
#pragma unroll
            for (int t = 0; t < 8; t++)
                h8[t] = (bf16_t)fmaxf((float)p8[t] + (float)uR[c][j][t] + (float)vR[c][j][t], 0.f);
            *(bf16x8*)&Hch[c][swz(r, col0 * 8)] = h8;
        }
    __syncthreads();   // barrier 3

    // ---- A2 both tiles: out = h · W2 ----
#pragma unroll
    for (int c = 0; c < 2; c++)
#pragma unroll
        for (int m = 0; m < 2; m++)
#pragma unroll
            for (int j = 0; j < 2; j++) acc[c][m][j] = (f32x4){0,0,0,0};
#pragma unroll
    for (int kk = 0; kk < 4; kk++) {
#pragma unroll
        for (int c = 0; c < 2; c++) {
            bf16x8 a0 = *(const bf16x8*)&Hch[c][swz(     col0, kk*32 + krow*8)];
            bf16x8 a1 = *(const bf16x8*)&Hch[c][swz(16 + col0, kk*32 + krow*8)];
#pragma unroll
            for (int j = 0; j < 2; j++) {
                acc[c][0][j] = __builtin_amdgcn_mfma_f32_16x16x32_bf16(a0, B2[kk][j], acc[c][0][j], 0,0,0);
                acc[c][1][j] = __builtin_amdgcn_mfma_f32_16x16x32_bf16(a1, B2[kk][j], acc[c][1][j], 0,0,0);
            }
        }
    }
    // epilogue both tiles: out = relu(acc + b2), non-temporal stores
#pragma unroll
    for (int c = 0; c < 2; c++)
#pragma unroll
        for (int m = 0; m < 2; m++)
#pragma unroll
            for (int j = 0; j < 2; j++)
#pragma unroll
                for (int ri = 0; ri < 4; ri++) {
                    int e = e0 + c * 32 + m*16 + krow*4 + ri;
                    if (e < E) {
                        float o = fmaxf(acc[c][m][j][ri] + bias2[j], 0.f);
                        __builtin_nontemporal_store(o, out + (long long)e * D + wv*32 + j*16 + col0);
                    }
                }
}

extern "C" void kernel_launch(void* const* d_in, const int* in_sizes, int n_in,
                              void* d_out, int out_size, void* d_ws, size_t ws_size,
                              hipStream_t stream) {
    const float* x  = (const float*)d_in[0];
    const float* ea = (const float*)d_in[1];
    const int*   ei = (const int*)d_in[2];
    const float* W1 = (const float*)d_in[3];
    const float* b1 = (const float*)d_in[4];
    const float* W2 = (const float*)d_in[5];
    const float* b2 = (const float*)d_in[6];
    float* out = (float*)d_out;

    const int E = in_sizes[1] / D;      // 400000
    const int N = in_sizes[0] / D;      // 50000

    bf16_t* wsl = (bf16_t*)d_ws;                  // 128 KB: slice-major tiles (uv_kernel)
    bf16_t* wsf = wsl + 4 * 16384;                // 64 KB: fragment-packed W1c/W2 (edge)
    bf16_t* uu  = wsf + 32768;                    // N*128 bf16
    bf16_t* vv  = uu + (size_t)N * D;             // N*128 bf16

    prep_weights_kernel<<<272, 256, 0, stream>>>(W1, W2, wsl, wsf);

    hipFuncSetAttribute(reinterpret_cast<const void*>(uv_kernel),
                        hipFuncAttributeMaxDynamicSharedMemorySize, UV_LDS);
    uv_kernel<<<(N + 255) / 256, 512, UV_LDS, stream>>>(x, wsl, b1, uu, vv, N);

    int nblocks = (E + 63) / 64;                  // 6250
    edge_kernel<<<nblocks, 256, 0, stream>>>(uu, vv, ea, ei, wsf, b2, out, E);
}

// Round 23
// 118.855 us; speedup vs baseline: 1.7618x; 1.1026x over previous
//
#include <hip/hip_runtime.h>
#include <hip/hip_bf16.h>

typedef __bf16 bf16_t;
typedef __bf16 bf16x8 __attribute__((ext_vector_type(8)));
typedef __bf16 bf16x4 __attribute__((ext_vector_type(4)));
typedef float  f32x4  __attribute__((ext_vector_type(4)));

#define D 128
#define UV_LDS 131072   // uv_kernel: 64KB weights + 8 x 8KB chunks

// LDS element-index swizzle: XOR multiples of 8 elems (16B) keep 4/8-elem groups intact.
__device__ __forceinline__ int swz(int r, int c) {
    return (r * D + c) ^ ((r & 7) << 3);
}

// prep: blocks 0..255: 4 transposed slice-major weight tiles ws[s][c][k]
//       blocks 256..271: fragment-packed W1c/W2 for the edge kernel:
//       wsf[((g*4+kk)*8+n)*64 + lane] (bf16x8) = Wt_g[n*16+(lane&15)][kk*32+(lane>>4)*8 ..+8]
__global__ void prep_weights_kernel(const float* __restrict__ W1,
                                    const float* __restrict__ W2,
                                    bf16_t* __restrict__ ws,
                                    bf16_t* __restrict__ wsf) {
    int b = blockIdx.x;
    if (b < 256) {
        int t = b * 256 + threadIdx.x;
        int s = t >> 14, r = t & 16383;
        int n = r >> 7, k = r & 127;
        float v = (s < 3) ? W1[(s * 128 + k) * 128 + n] : W2[k * 128 + n];
        ws[t] = (bf16_t)v;
    } else {
        int t = (b - 256) * 256 + threadIdx.x;      // 0..4095
        int lane = t & 63, f = t >> 6;              // f = (g*4+kk)*8+n
        int n = f & 7, kk = (f >> 3) & 3, g = f >> 5;
        int c = n * 16 + (lane & 15);
        int k0 = kk * 32 + (lane >> 4) * 8;
        bf16x8 v;
#pragma unroll
        for (int j = 0; j < 8; j++) {
            int k = k0 + j;
            float w = (g == 0) ? W1[(256 + k) * 128 + c] : W2[k * 128 + c];
            v[j] = (bf16_t)w;
        }
        *(bf16x8*)(wsf + t * 8) = v;
    }
}

// u = x·W1a + b1, v = x·W1b   (bf16 row-major, gather-ready)  [proven R10 kernel]
// x loads are non-temporal (single-use stream) to keep L2/L3 clean.
__global__ __launch_bounds__(512, 2)
void uv_kernel(const float* __restrict__ x, const bf16_t* __restrict__ ws,
               const float* __restrict__ b1, bf16_t* __restrict__ u,
               bf16_t* __restrict__ v, int N) {
    extern __shared__ __align__(16) bf16_t lds[];
    const int tid = threadIdx.x, lane = tid & 63, wv = tid >> 6;
    const int col0 = lane & 15, krow = lane >> 4, l31 = lane & 31, half = lane >> 5;
    const int gr = lane >> 4, gc = (lane & 15) * 8;
    const int n0 = blockIdx.x * 256 + wv * 32;
    bf16_t* Ach = lds + 32768 + wv * 4096;

    f32x4 xb[16];
#pragma unroll
    for (int j = 0; j < 16; j++) {
        int node = min(n0 + j * 2 + half, N - 1);
        xb[j] = __builtin_nontemporal_load((const f32x4*)(x + (long long)node * D + l31 * 4));
    }
#pragma unroll
    for (int s = 0; s < 2; s++)
#pragma unroll
        for (int j = 0; j < 4; j++) {
            int row = j * 32 + (tid >> 4), slot = (tid & 15) * 8;
            bf16x8 w = *(const bf16x8*)(ws + s * 16384 + row * 128 + slot);
            *(bf16x8*)&lds[s * 16384 + swz(row, slot)] = w;
        }
    float bias1[8];
#pragma unroll
    for (int n = 0; n < 8; n++) bias1[n] = b1[n * 16 + col0];
#pragma unroll
    for (int j = 0; j < 16; j++) {
        f32x4 vv = xb[j];
        bf16x4 hv = { (bf16_t)vv.x, (bf16_t)vv.y, (bf16_t)vv.z, (bf16_t)vv.w };
        *(bf16x4*)&Ach[swz(j * 2 + half, l31 * 4)] = hv;
    }
    __syncthreads();

    f32x4 aU[2][8], aV[2][8];
#pragma unroll
    for (int m = 0; m < 2; m++)
#pragma unroll
        for (int n = 0; n < 8; n++) { aU[m][n] = (f32x4){0,0,0,0}; aV[m][n] = (f32x4){0,0,0,0}; }
#pragma unroll
    for (int kk = 0; kk < 4; kk++) {
        bf16x8 a0 = *(const bf16x8*)&Ach[swz(col0, kk*32 + krow*8)];
        bf16x8 a1 = *(const bf16x8*)&Ach[swz(16 + col0, kk*32 + krow*8)];
#pragma unroll
        for (int n = 0; n < 8; n++) {
            bf16x8 bU = *(const bf16x8*)&lds[swz(n*16 + col0, kk*32 + krow*8)];
            bf16x8 bV = *(const bf16x8*)&lds[16384 + swz(n*16 + col0, kk*32 + krow*8)];
            aU[0][n] = __builtin_amdgcn_mfma_f32_16x16x32_bf16(a0, bU, aU[0][n], 0,0,0);
            aU[1][n] = __builtin_amdgcn_mfma_f32_16x16x32_bf16(a1, bU, aU[1][n], 0,0,0);
            aV[0][n] = __builtin_amdgcn_mfma_f32_16x16x32_bf16(a0, bV, aV[0][n], 0,0,0);
            aV[1][n] = __builtin_amdgcn_mfma_f32_16x16x32_bf16(a1, bV, aV[1][n], 0,0,0);
        }
    }
#pragma unroll
    for (int m = 0; m < 2; m++)
#pragma unroll
        for (int n = 0; n < 8; n++)
#pragma unroll
            for (int ri = 0; ri < 4; ri++)
                Ach[swz(m*16 + krow*4 + ri, n*16 + col0)] = (bf16_t)(aU[m][n][ri] + bias1[n]);
#pragma unroll
    for (int j = 0; j < 8; j++) {
        int r = j * 4 + gr, node = n0 + r;
        if (node < N) *(bf16x8*)(u + (long long)node * D + gc) = *(const bf16x8*)&Ach[swz(r, gc)];
    }
#pragma unroll
    for (int m = 0; m < 2; m++)
#pragma unroll
        for (int n = 0; n < 8; n++)
#pragma unroll
            for (int ri = 0; ri < 4; ri++)
                Ach[swz(m*16 + krow*4 + ri, n*16 + col0)] = (bf16_t)(aV[m][n][ri]);
#pragma unroll
    for (int j = 0; j < 8; j++) {
        int r = j * 4 + gr, node = n0 + r;
        if (node < N) *(bf16x8*)(v + (long long)node * D + gc) = *(const bf16x8*)&Ach[swz(r, gc)];
    }
}

// Two independent 32-edge tiles per block, 4 waves; wave wv owns output cols
// [wv*32, wv*32+32) of both tiles. B-fragments in regs/L1.
// ea loads NON-TEMPORAL (keeps L2/L3 reserved for u/v gather hot set, R22: -8MB
// FETCH, -4us). out stores REGULAR (R22 showed NT stores cause partial-line
// write amplification: WRITE 200->270MB).
// out = relu( relu(ea·W1c + u[src] + v[dst]) · W2 + b2 )
__global__ __launch_bounds__(256, 3)
void edge_kernel(const bf16_t* __restrict__ u, const bf16_t* __restrict__ v,
                 const float* __restrict__ ea, const int* __restrict__ ei,
                 const bf16_t* __restrict__ wsf, const float* __restrict__ b2,
                 float* __restrict__ out, int E) {
    __shared__ __align__(16) bf16_t Ach[2][32 * D];   // ea tiles (bf16, swizzled)
    __shared__ __align__(16) bf16_t Hch[2][32 * D];   // p then h tiles

    const int tid  = threadIdx.x, lane = tid & 63, wv = tid >> 6;   // 4 waves
    const int col0 = lane & 15, krow = lane >> 4, l31 = lane & 31;
    const int e0   = blockIdx.x * 64;                // tile c: rows e0 + c*32 ..

    // ---- prologue: ea loads (non-temporal) + indices + B1 only ----
    f32x4 eaR[2][4];
#pragma unroll
    for (int c = 0; c < 2; c++)
#pragma unroll
        for (int j = 0; j < 4; j++) {
            int r = wv * 8 + j * 2 + (lane >> 5);
            int e = min(e0 + c * 32 + r, E - 1);
            eaR[c][j] = __builtin_nontemporal_load((const f32x4*)(ea + (long long)e * D + l31 * 4));
        }
    int sidx[2], didx[2];
#pragma unroll
    for (int c = 0; c < 2; c++) {
        int er8 = min(e0 + c * 32 + wv * 8 + (lane & 7), E - 1);
        sidx[c] = ei[er8];
        didx[c] = ei[E + er8];
    }
    bf16x8 B1[4][2];
#pragma unroll
    for (int kk = 0; kk < 4; kk++)
#pragma unroll
        for (int j = 0; j < 2; j++)
            B1[kk][j] = *(const bf16x8*)(wsf + (((kk) * 8 + (wv * 2 + j)) * 64 + lane) * 8);
    float bias2[2];
    bias2[0] = b2[wv * 32 + col0];
    bias2[1] = b2[wv * 32 + 16 + col0];

    // ---- ea -> Ach (both tiles) ----
#pragma unroll
    for (int c = 0; c < 2; c++)
#pragma unroll
        for (int j = 0; j < 4; j++) {
            int r = wv * 8 + j * 2 + (lane >> 5);
            f32x4 vv = eaR[c][j];
            bf16x4 hv = { (bf16_t)vv.x, (bf16_t)vv.y, (bf16_t)vv.z, (bf16_t)vv.w };
            *(bf16x4*)&Ach[c][swz(r, l31 * 4)] = hv;
        }
    __syncthreads();   // barrier 1 (drains ea/ei/B1 — all needed right now anyway)

    // ---- issue u/v gathers + B2 AFTER the drain: they fly under A1 + p-writes ----
    bf16x8 uR[2][2], vR[2][2];
#pragma unroll
    for (int c = 0; c < 2; c++)
#pragma unroll
        for (int j = 0; j < 2; j++) {
            int gi = __shfl(sidx[c], j * 4 + (lane >> 4));   // 4 rows/instr, 256B/row
            uR[c][j] = *(const bf16x8*)(u + (long long)gi * D + col0 * 8);
            int gj = __shfl(didx[c], j * 4 + (lane >> 4));
            vR[c][j] = *(const bf16x8*)(v + (long long)gj * D + col0 * 8);
        }
    bf16x8 B2[4][2];
#pragma unroll
    for (int kk = 0; kk < 4; kk++)
#pragma unroll
        for (int j = 0; j < 2; j++)
            B2[kk][j] = *(const bf16x8*)(wsf + (((4 + kk) * 8 + (wv * 2 + j)) * 64 + lane) * 8);

    // ---- A1 both tiles: p = ea · W1c ----
    f32x4 acc[2][2][2];   // [tile][m][j]
#pragma unroll
    for (int c = 0; c < 2; c++)
#pragma unroll
        for (int m = 0; m < 2; m++)
#pragma unroll
            for (int j = 0; j < 2; j++) acc[c][m][j] = (f32x4){0,0,0,0};
#pragma unroll
    for (int kk = 0; kk < 4; kk++) {
#pragma unroll
        for (int c = 0; c < 2; c++) {
            bf16x8 a0 = *(const bf16x8*)&Ach[c][swz(     col0, kk*32 + krow*8)];
            bf16x8 a1 = *(const bf16x8*)&Ach[c][swz(16 + col0, kk*32 + krow*8)];
#pragma unroll
            for (int j = 0; j < 2; j++) {
                acc[c][0][j] = __builtin_amdgcn_mfma_f32_16x16x32_bf16(a0, B1[kk][j], acc[c][0][j], 0,0,0);
                acc[c][1][j] = __builtin_amdgcn_mfma_f32_16x16x32_bf16(a1, B1[kk][j], acc[c][1][j], 0,0,0);
            }
        }
    }
    // p -> Hch (C-space scalar writes), both tiles
#pragma unroll
    for (int c = 0; c < 2; c++)
#pragma unroll
        for (int m = 0; m < 2; m++)
#pragma unroll
            for (int j = 0; j < 2; j++)
#pragma unroll
                for (int ri = 0; ri < 4; ri++)
                    Hch[c][swz(m*16 + krow*4 + ri, wv*32 + j*16 + col0)] = (bf16_t)acc[c][m][j][ri];
    __syncthreads();   // barrier 2

    // ---- h = relu(p + u + v), both tiles (row-space b128 RMW, fused in regs) ----
#pragma unroll
    for (int c = 0; c < 2; c++)
#pragma unroll
        for (int j = 0; j < 2; j++) {
            int r = wv * 8 + j * 4 + (lane >> 4);
            bf16x8 p8 = *(const bf16x8*)&Hch[c][swz(r, col0 * 8)];
            bf16x8 h8;
#pragma unroll
            for (int t = 0; t < 8; t++)
                h8[t] = (bf16_t)fmaxf((float)p8[t] + (float)uR[c][j][t] + (float)vR[c][j][t], 0.f);
            *(bf16x8*)&Hch[c][swz(r, col0 * 8)] = h8;
        }
    __syncthreads();   // barrier 3

    // ---- A2 both tiles: out = h · W2 ----
#pragma unroll
    for (int c = 0; c < 2; c++)
#pragma unroll
        for (int m = 0; m < 2; m++)
#pragma unroll
            for (int j = 0; j < 2; j++) acc[c][m][j] = (f32x4){0,0,0,0};
#pragma unroll
    for (int kk = 0; kk < 4; kk++) {
#pragma unroll
        for (int c = 0; c < 2; c++) {
            bf16x8 a0 = *(const bf16x8*)&Hch[c][swz(     col0, kk*32 + krow*8)];
            bf16x8 a1 = *(const bf16x8*)&Hch[c][swz(16 + col0, kk*32 + krow*8)];
#pragma unroll
            for (int j = 0; j < 2; j++) {
                acc[c][0][j] = __builtin_amdgcn_mfma_f32_16x16x32_bf16(a0, B2[kk][j], acc[c][0][j], 0,0,0);
                acc[c][1][j] = __builtin_amdgcn_mfma_f32_16x16x32_bf16(a1, B2[kk][j], acc[c][1][j], 0,0,0);
            }
        }
    }
    // epilogue both tiles: out = relu(acc + b2), regular (write-combining) stores
#pragma unroll
    for (int c = 0; c < 2; c++)
#pragma unroll
        for (int m = 0; m < 2; m++)
#pragma unroll
            for (int j = 0; j < 2; j++)
#pragma unroll
                for (int ri = 0; ri < 4; ri++) {
                    int e = e0 + c * 32 + m*16 + krow*4 + ri;
                    if (e < E)
                        out[(long long)e * D + wv*32 + j*16 + col0] = fmaxf(acc[c][m][j][ri] + bias2[j], 0.f);
                }
}

extern "C" void kernel_launch(void* const* d_in, const int* in_sizes, int n_in,
                              void* d_out, int out_size, void* d_ws, size_t ws_size,
                              hipStream_t stream) {
    const float* x  = (const float*)d_in[0];
    const float* ea = (const float*)d_in[1];
    const int*   ei = (const int*)d_in[2];
    const float* W1 = (const float*)d_in[3];
    const float* b1 = (const float*)d_in[4];
    const float* W2 = (const float*)d_in[5];
    const float* b2 = (const float*)d_in[6];
    float* out = (float*)d_out;

    const int E = in_sizes[1] / D;      // 400000
    const int N = in_sizes[0] / D;      // 50000

    bf16_t* wsl = (bf16_t*)d_ws;                  // 128 KB: slice-major tiles (uv_kernel)
    bf16_t* wsf = wsl + 4 * 16384;                // 64 KB: fragment-packed W1c/W2 (edge)
    bf16_t* uu  = wsf + 32768;                    // N*128 bf16
    bf16_t* vv  = uu + (size_t)N * D;             // N*128 bf16

    prep_weights_kernel<<<272, 256, 0, stream>>>(W1, W2, wsl, wsf);

    hipFuncSetAttribute(reinterpret_cast<const void*>(uv_kernel),
                        hipFuncAttributeMaxDynamicSharedMemorySize, UV_LDS);
    uv_kernel<<<(N + 255) / 256, 512, UV_LDS, stream>>>(x, wsl, b1, uu, vv, N);

    int nblocks = (E + 63) / 64;                  // 6250
    edge_kernel<<<nblocks, 256, 0, stream>>>(uu, vv, ea, ei, wsf, b2, out, E);
}